// Round 1
// baseline (3663.435 us; speedup 1.0000x reference)
//
#include <hip/hip_runtime.h>

#define B_   64
#define T_   512
#define HID_ 512
#define H_   256
#define G4   1024
#define N2   2048
#define M_   (B_*T_)
#define NL_  9

typedef short short8 __attribute__((ext_vector_type(8)));
typedef float f32x4 __attribute__((ext_vector_type(4)));
typedef _Float16 f16x2 __attribute__((ext_vector_type(2)));

__device__ inline float bf2f(unsigned short u) {
  unsigned int x = ((unsigned int)u) << 16;
  return __builtin_bit_cast(float, x);
}
__device__ inline unsigned short f2bf(float f) {
  unsigned int u = __builtin_bit_cast(unsigned int, f);
  return (unsigned short)((u + 0x7fffu + ((u >> 16) & 1u)) >> 16);
}
__device__ inline unsigned short f2h(float f) {
  _Float16 h = (_Float16)f;
  return __builtin_bit_cast(unsigned short, h);
}
__device__ inline float fdot2(unsigned int w, unsigned int h, float acc) {
#if __has_builtin(__builtin_amdgcn_fdot2)
  return __builtin_amdgcn_fdot2(__builtin_bit_cast(f16x2, w),
                                __builtin_bit_cast(f16x2, h), acc, false);
#else
  f16x2 a = __builtin_bit_cast(f16x2, w), b = __builtin_bit_cast(f16x2, h);
  return acc + (float)a[0]*(float)b[0] + (float)a[1]*(float)b[1];
#endif
}
__device__ inline float sigm(float x)     { return 1.f / (1.f + __expf(-x)); }
__device__ inline float tanhfast(float x) { return 1.f - 2.f / (__expf(2.f*x) + 1.f); }

// ---------------- prep kernels ----------------
__global__ void k_cast_bf16(const float* __restrict__ src, unsigned short* __restrict__ dst, int n) {
  int i = blockIdx.x*256 + threadIdx.x;
  if (i < n) dst[i] = f2bf(src[i]);
}

// w_hh (2,2,1024,256) fp32 -> fp16 pairs: k<192 -> wreg[(ld*96+kp)*1024+col]
//                                          k>=192 -> wlds[((ld*8+blk)*1024+col)*4+q]
__global__ void k_pack_whh(const float* __restrict__ whh, unsigned int* __restrict__ wreg,
                           unsigned int* __restrict__ wlds) {
  int idx = blockIdx.x*256 + threadIdx.x;           // 2*2*1024*128 = 524288
  int kp  = idx & 127;
  int col = (idx >> 7) & 1023;
  int ld  = idx >> 17;                              // l*2+d
  const float* src = whh + ((size_t)ld*1024 + col)*256 + kp*2;
  unsigned int pack = (unsigned int)f2h(src[0]) | ((unsigned int)f2h(src[1]) << 16);
  if (kp < 96) {
    wreg[((size_t)ld*96 + kp)*1024 + col] = pack;
  } else {
    int kq = kp - 96, blk = kq >> 2, q = kq & 3;
    wlds[(((size_t)ld*8 + blk)*1024 + col)*4 + q] = pack;
  }
}

__global__ void k_bias_sum(const float* __restrict__ bi, const float* __restrict__ bh,
                           float* __restrict__ bs) {
  int i = blockIdx.x*256 + threadIdx.x;
  if (i < 4096) bs[i] = bi[i] + bh[i];
}

__global__ void k_cls_pad(const float* __restrict__ w, unsigned short* __restrict__ dst) {
  int i = blockIdx.x*256 + threadIdx.x;             // 16*512
  if (i < 16*512) {
    int n = i >> 9, k = i & 511;
    dst[i] = (n < NL_) ? f2bf(w[n*512 + k]) : (unsigned short)0;
  }
}

__global__ void k_embed(const int* __restrict__ ids, const float* __restrict__ emb,
                        unsigned short* __restrict__ x0) {
  int idx = blockIdx.x*256 + threadIdx.x;           // M_*128
  int m  = idx >> 7;
  int e4 = (idx & 127) << 2;
  int id = ids[m];
  float4 v = *(const float4*)(emb + (size_t)id*HID_ + e4);
  unsigned short* dst = x0 + (size_t)m*HID_ + e4;
  dst[0]=f2bf(v.x); dst[1]=f2bf(v.y); dst[2]=f2bf(v.z); dst[3]=f2bf(v.w);
}

// ---------------- input-projection GEMM (bf16 MFMA, fragments direct from L2) ----------------
// C[m][n] = sum_k A[m][k]*Bt[n][k] + bias[n],  M=32768 N=2048 K=512, out bf16
__global__ __launch_bounds__(256) void k_gemm_inproj(const unsigned short* __restrict__ A,
    const unsigned short* __restrict__ Bt, const float* __restrict__ bias,
    unsigned short* __restrict__ C) {
  int lane = threadIdx.x & 63, wave = threadIdx.x >> 6;
  int n0 = blockIdx.x * 64;
  int m0 = blockIdx.y * 64 + wave * 16;
  int r = lane & 15, kg = lane >> 4;
  const short8* Ap = (const short8*)(A + (size_t)(m0 + r)*512 + kg*8);
  const short8* Bp = (const short8*)(Bt + (size_t)(n0 + r)*512 + kg*8);
  f32x4 acc0 = {0,0,0,0}, acc1 = {0,0,0,0}, acc2 = {0,0,0,0}, acc3 = {0,0,0,0};
  #pragma unroll
  for (int kb = 0; kb < 16; kb++) {
    short8 a  = Ap[kb*4];
    short8 b0 = Bp[kb*4];
    short8 b1 = Bp[kb*4 + 1024];     // +16 rows (16*512/8)
    short8 b2 = Bp[kb*4 + 2048];
    short8 b3 = Bp[kb*4 + 3072];
    acc0 = __builtin_amdgcn_mfma_f32_16x16x32_bf16(a, b0, acc0, 0, 0, 0);
    acc1 = __builtin_amdgcn_mfma_f32_16x16x32_bf16(a, b1, acc1, 0, 0, 0);
    acc2 = __builtin_amdgcn_mfma_f32_16x16x32_bf16(a, b2, acc2, 0, 0, 0);
    acc3 = __builtin_amdgcn_mfma_f32_16x16x32_bf16(a, b3, acc3, 0, 0, 0);
  }
  int row0 = m0 + (lane >> 4)*4, col = lane & 15;
  #pragma unroll
  for (int s = 0; s < 4; s++) {
    f32x4 acc = (s==0) ? acc0 : (s==1) ? acc1 : (s==2) ? acc2 : acc3;
    int n = n0 + s*16 + col;
    float bb = bias[n];
    #pragma unroll
    for (int rr = 0; rr < 4; rr++)
      C[(size_t)(row0+rr)*N2 + n] = f2bf(acc[rr] + bb);
  }
}

// ---------------- classifier GEMM: logits[m][l] (N padded to 16, fp32 out) ----------------
__global__ __launch_bounds__(256) void k_cls(const unsigned short* __restrict__ X,
    const unsigned short* __restrict__ Wb, const float* __restrict__ cb,
    float* __restrict__ out) {
  int lane = threadIdx.x & 63, wave = threadIdx.x >> 6;
  int m0 = blockIdx.x*64 + wave*16;
  int r = lane & 15, kg = lane >> 4;
  const short8* Ap = (const short8*)(X  + (size_t)(m0 + r)*512 + kg*8);
  const short8* Bp = (const short8*)(Wb + (size_t)r*512 + kg*8);
  f32x4 acc = {0,0,0,0};
  #pragma unroll
  for (int kb = 0; kb < 16; kb++)
    acc = __builtin_amdgcn_mfma_f32_16x16x32_bf16(Ap[kb*4], Bp[kb*4], acc, 0, 0, 0);
  int row0 = m0 + (lane >> 4)*4, col = lane & 15;
  if (col < NL_) {
    float bb = cb[col];
    #pragma unroll
    for (int rr = 0; rr < 4; rr++)
      out[(size_t)(row0+rr)*NL_ + col] = acc[rr] + bb;
  }
}

// ---------------- LSTM recurrence: 1 block per (batch, dir), weights resident ----------------
#define DOT4(ACC, W0, W1, W2, W3, HH) do { \
  ACC = fdot2(W0, (HH).x, ACC); ACC = fdot2(W1, (HH).y, ACC); \
  ACC = fdot2(W2, (HH).z, ACC); ACC = fdot2(W3, (HH).w, ACC); } while(0)

__global__ __launch_bounds__(512, 2) void k_rec(const unsigned short* __restrict__ xp,
    const unsigned int* __restrict__ wreg, const unsigned int* __restrict__ wlds,
    unsigned short* __restrict__ xout, int layer) {
  extern __shared__ char smem[];
  unsigned int* wl    = (unsigned int*)smem;                     // 8*1024*4 uints = 128KB
  float*        gates = (float*)(smem + 131072);                 // 1024 f32
  unsigned int* hpair = (unsigned int*)(smem + 131072 + 4096);   // 128 uints (256 fp16)
  int t = threadIdx.x;
  int b = blockIdx.x >> 1, d = blockIdx.x & 1;
  int ld = layer*2 + d;
  {
    const uint4* src = (const uint4*)(wlds + (size_t)ld*32768);
    uint4* dst = (uint4*)wl;
    #pragma unroll
    for (int i = 0; i < 16; i++) dst[t + i*512] = src[t + i*512];
  }
  int c0 = t, c1 = t + 512;
  unsigned int wr0[96], wr1[96];
  {
    const unsigned int* wr = wreg + (size_t)ld*96*1024;
    #pragma unroll
    for (int kp = 0; kp < 96; kp++) { wr0[kp] = wr[kp*1024 + c0]; wr1[kp] = wr[kp*1024 + c1]; }
  }
  if (t < 128) hpair[t] = 0u;
  float cst = 0.f;
  const unsigned short* xbase = xp + (size_t)b*T_*N2 + (size_t)d*G4;
  unsigned short* obase = xout + (size_t)b*T_*HID_ + d*H_;
  __syncthreads();
  int tt = d ? (T_-1) : 0;
  float nxt0 = bf2f(xbase[(size_t)tt*N2 + c0]);
  float nxt1 = bf2f(xbase[(size_t)tt*N2 + c1]);
  #pragma unroll 1
  for (int step = 0; step < T_; step++) {
    float a0 = nxt0, a1 = nxt1, p0 = 0.f, p1 = 0.f;
    int ttn = d ? (T_-2-step) : (step+1);
    if (step < T_-1) {                 // prefetch next step's xp (hides HBM latency)
      nxt0 = bf2f(xbase[(size_t)ttn*N2 + c0]);
      nxt1 = bf2f(xbase[(size_t)ttn*N2 + c1]);
    }
    const uint4* hp4 = (const uint4*)hpair;
    #pragma unroll
    for (int kb = 0; kb < 24; kb++) {   // register-resident part: k in [0,192)
      uint4 hh = hp4[kb];
      if (kb & 1) {
        DOT4(p0, wr0[4*kb+0], wr0[4*kb+1], wr0[4*kb+2], wr0[4*kb+3], hh);
        DOT4(p1, wr1[4*kb+0], wr1[4*kb+1], wr1[4*kb+2], wr1[4*kb+3], hh);
      } else {
        DOT4(a0, wr0[4*kb+0], wr0[4*kb+1], wr0[4*kb+2], wr0[4*kb+3], hh);
        DOT4(a1, wr1[4*kb+0], wr1[4*kb+1], wr1[4*kb+2], wr1[4*kb+3], hh);
      }
    }
    #pragma unroll
    for (int blk = 0; blk < 8; blk++) { // LDS-resident part: k in [192,256)
      uint4 hh = hp4[24 + blk];
      const uint4* wb = (const uint4*)wl + (size_t)blk*1024;
      uint4 w0 = wb[c0], w1 = wb[c1];
      if (blk & 1) {
        DOT4(p0, w0.x, w0.y, w0.z, w0.w, hh);
        DOT4(p1, w1.x, w1.y, w1.z, w1.w, hh);
      } else {
        DOT4(a0, w0.x, w0.y, w0.z, w0.w, hh);
        DOT4(a1, w1.x, w1.y, w1.z, w1.w, hh);
      }
    }
    gates[c0] = a0 + p0;
    gates[c1] = a1 + p1;
    __syncthreads();
    if (t < H_) {
      float gi = sigm(gates[t]);
      float gf = sigm(gates[H_ + t]);
      float gg = tanhfast(gates[2*H_ + t]);
      float go = sigm(gates[3*H_ + t]);
      cst = gf*cst + gi*gg;
      float h = go * tanhfast(cst);
      ((_Float16*)hpair)[t] = (_Float16)h;
      obase[(size_t)tt*HID_ + t] = f2bf(h);
    }
    __syncthreads();
    tt = ttn;
  }
}

// ---------------- CRF ----------------
__global__ void k_zero(float* out) { if (threadIdx.x == 0) out[0] = 0.f; }

__global__ void k_crf(const float* __restrict__ logits, const int* __restrict__ labels,
                      const float* __restrict__ st, const float* __restrict__ et,
                      const float* __restrict__ tr, float* __restrict__ out) {
  int b = blockIdx.x, lane = threadIdx.x;
  bool act = lane < NL_;
  const float* lb = logits + (size_t)b*T_*NL_;
  float trc[9];
  #pragma unroll
  for (int i = 0; i < 9; i++) trc[i] = act ? tr[i*9 + lane] : 0.f;
  float em = act ? lb[lane] : -1e30f;
  float alpha = act ? (st[lane] + em) : -1e30f;
  int prev = labels[b*T_];
  float num = __shfl(alpha, prev);
  for (int ttt = 1; ttt < T_; ttt++) {
    em = act ? lb[ttt*NL_ + lane] : -1e30f;
    float vv[9]; float mx = -1e30f;
    #pragma unroll
    for (int i = 0; i < 9; i++) { vv[i] = __shfl(alpha, i) + trc[i]; mx = fmaxf(mx, vv[i]); }
    float s = 0.f;
    #pragma unroll
    for (int i = 0; i < 9; i++) s += __expf(vv[i] - mx);
    alpha = act ? (mx + __logf(s) + em) : -1e30f;
    int tag = labels[b*T_ + ttt];
    float emtag = __shfl(em, tag);
    if (lane == 0) num += tr[prev*9 + tag] + emtag;
    prev = tag;
  }
  float fa = act ? (alpha + et[lane]) : -1e30f;
  float mx = -1e30f;
  #pragma unroll
  for (int i = 0; i < 9; i++) mx = fmaxf(mx, __shfl(fa, i));
  float s = 0.f;
  #pragma unroll
  for (int i = 0; i < 9; i++) s += __expf(__shfl(fa, i) - mx);
  float denom = mx + __logf(s);
  if (lane == 0) {
    num += et[prev];
    atomicAdd(out, denom - num);
  }
}

// ---------------- launch ----------------
extern "C" void kernel_launch(void* const* d_in, const int* in_sizes, int n_in,
                              void* d_out, int out_size, void* d_ws, size_t ws_size,
                              hipStream_t stream) {
  const int*   ids    = (const int*)d_in[0];
  const int*   labels = (const int*)d_in[1];
  const float* emb    = (const float*)d_in[2];
  const float* w_ih   = (const float*)d_in[3];
  const float* w_hh   = (const float*)d_in[4];
  const float* b_ih   = (const float*)d_in[5];
  const float* b_hh   = (const float*)d_in[6];
  const float* cls_w  = (const float*)d_in[7];
  const float* cls_b  = (const float*)d_in[8];
  const float* st     = (const float*)d_in[9];
  const float* et     = (const float*)d_in[10];
  const float* tr     = (const float*)d_in[11];
  float* out = (float*)d_out;

  char* ws = (char*)d_ws;
  unsigned short* xp    = (unsigned short*)(ws);                  // 134,217,728
  unsigned short* x0    = (unsigned short*)(ws + 134217728);      //  33,554,432
  unsigned short* x1    = (unsigned short*)(ws + 167772160);      //  33,554,432
  unsigned short* wbi   = (unsigned short*)(ws + 201326592);      //   4,194,304
  unsigned int*   wreg  = (unsigned int*)  (ws + 205520896);      //   1,572,864
  unsigned int*   wldsg = (unsigned int*)  (ws + 207093760);      //     524,288
  float*          bsum  = (float*)         (ws + 207618048);      //      16,384
  unsigned short* clswb = (unsigned short*)(ws + 207634432);      //      16,384
  float*          logit = (float*)         (ws + 207650816);      //   1,179,648  (end ~199.1 MiB)

  const int REC_SMEM = 131072 + 4096 + 512;
  hipFuncSetAttribute((const void*)k_rec, hipFuncAttributeMaxDynamicSharedMemorySize, REC_SMEM);

  k_cast_bf16<<<8192, 256, 0, stream>>>(w_ih, wbi, 2*N2*512);
  k_pack_whh <<<2048, 256, 0, stream>>>(w_hh, wreg, wldsg);
  k_bias_sum <<<16,   256, 0, stream>>>(b_ih, b_hh, bsum);
  k_cls_pad  <<<32,   256, 0, stream>>>(cls_w, clswb);
  k_embed    <<<16384,256, 0, stream>>>(ids, emb, x0);

  dim3 ggrid(32, 512);
  k_gemm_inproj<<<ggrid, 256, 0, stream>>>(x0, wbi, bsum, xp);
  k_rec<<<128, 512, REC_SMEM, stream>>>(xp, wreg, wldsg, x1, 0);
  k_gemm_inproj<<<ggrid, 256, 0, stream>>>(x1, wbi + (size_t)N2*512, bsum + 2048, xp);
  k_rec<<<128, 512, REC_SMEM, stream>>>(xp, wreg, wldsg, x0, 1);   // x2 reuses x0
  k_cls<<<512, 256, 0, stream>>>(x0, clswb, cls_b, logit);
  k_zero<<<1, 64, 0, stream>>>(out);
  k_crf<<<64, 64, 0, stream>>>(logit, labels, st, et, tr, out);
}